// Round 1
// baseline (419.717 us; speedup 1.0000x reference)
//
#include <hip/hip_runtime.h>
#include <hip/hip_bf16.h>
#include <cstdint>

// DynamicPlasticityModule collapsed:
//   combined = x @ A^T + c1,  A  = Wc_eff @ Wp,  Wc_eff[j,:] = gate[j>>5]*Wc[j,:]
//   out      = x @ B2^T + c2, B2 = Wo @ A
// Single fused GEMM x[131072,256] @ Wbig^T[512,256] (bf16 MFMA, fp32 accum).

#define BATCH 131072
#define TAIL ((size_t)2 * BATCH * 256)

typedef unsigned short u16;
typedef __attribute__((ext_vector_type(8))) short short8;
typedef __attribute__((ext_vector_type(4))) float floatx4;

__device__ __forceinline__ short f2bf(float f) {
    union { float f; unsigned u; } v; v.f = f;
    unsigned u = v.u;
    u += 0x7fffu + ((u >> 16) & 1u);   // RNE
    return (short)(u >> 16);
}

// ---------------- k1: alignment gates (exact fp32) ----------------
__global__ void k_align(const float* __restrict__ pre, const float* __restrict__ post,
                        float* __restrict__ gate_ws, float* __restrict__ out_tail) {
    int k = threadIdx.x;
    if (k < 8) {
        float na = 0.f, nb = 0.f, dp = 0.f;
        for (int i = 0; i < 32; ++i) {
            float a = pre[k * 256 + i], b = post[k * 32 + i];
            na += a * a; nb += b * b; dp += a * b;
        }
        float denom = fmaxf(sqrtf(na), 1e-12f) * fmaxf(sqrtf(nb), 1e-12f);
        float sim = dp / denom;
        float align = 1.f / (1.f + expf(-sim));       // GAIN = 1
        float gate = (align >= 0.3f) ? align : 0.f;   // THRESH = 0.3
        gate_ws[k] = gate;
        out_tail[k] = gate;        // alignments = align*(align>=thresh) == gate
        out_tail[8 + k] = 1.f;     // allocation_mask
    }
}

// ---------------- k2: A = Wc_eff @ Wp (fp32), c1 = Wc_eff @ bp ----------------
__global__ __launch_bounds__(256) void k_makeA(
        const float* __restrict__ Wc, const float* __restrict__ Wp,
        const float* __restrict__ bp, const float* __restrict__ gate_ws,
        float* __restrict__ A, float* __restrict__ bias512, u16* __restrict__ Wbig) {
    int j = blockIdx.x, t = threadIdx.x;
    __shared__ float wc[256];
    __shared__ float red[256];
    float g = gate_ws[j >> 5];
    float v = Wc[j * 256 + t];
    wc[t] = v;
    red[t] = v * bp[t];
    __syncthreads();
    for (int s = 128; s > 0; s >>= 1) {
        if (t < s) red[t] += red[t + s];
        __syncthreads();
    }
    if (t == 0) bias512[256 + j] = g * red[0];   // c1[j]
    float acc = 0.f;
#pragma unroll 16
    for (int i = 0; i < 256; ++i) acc += wc[i] * Wp[i * 256 + t];
    acc *= g;
    A[j * 256 + t] = acc;
    Wbig[(256 + j) * 256 + t] = (u16)f2bf(acc);  // rows 256..511 of Wbig = A
}

// ---------------- k3: B2 = Wo @ A (fp32), c2 = Wo @ c1 + bo ----------------
__global__ __launch_bounds__(256) void k_makeB2(
        const float* __restrict__ Wo, const float* __restrict__ bo,
        const float* __restrict__ A, float* __restrict__ bias512,
        u16* __restrict__ Wbig) {
    int tt = blockIdx.x, t = threadIdx.x;
    __shared__ float wo[256];
    __shared__ float red[256];
    float v = Wo[tt * 256 + t];
    wo[t] = v;
    red[t] = v * bias512[256 + t];   // c1
    __syncthreads();
    for (int s = 128; s > 0; s >>= 1) {
        if (t < s) red[t] += red[t + s];
        __syncthreads();
    }
    if (t == 0) bias512[tt] = red[0] + bo[tt];   // c2[tt]
    float acc = 0.f;
#pragma unroll 16
    for (int i = 0; i < 256; ++i) acc += wo[i] * A[i * 256 + t];
    Wbig[tt * 256 + t] = (u16)f2bf(acc);         // rows 0..255 of Wbig = B2
}

// ---------------- k4: fused big GEMM, m97-style 128x128, BK=32 ----------------
#define AS3(p) ((__attribute__((address_space(3))) void*)(p))
#define AS1(p) ((const __attribute__((address_space(1))) void*)(p))

__global__ __launch_bounds__(256, 2) void k_gemm(
        const float* __restrict__ x, const u16* __restrict__ Wbig,
        const float* __restrict__ bias512, float* __restrict__ out) {
    __shared__ float sA[128 * 32];   // x tile, fp32, row-major (rows=m, 32 k)
    __shared__ u16  sB[128 * 32];    // Wbig tile, bf16, row-major (rows=n, 32 k)

    const int tid = threadIdx.x;
    const int wave = tid >> 6, lane = tid & 63;
    const int lr = lane & 15, quad = lane >> 4;
    const int b = blockIdx.x;
    // 32-block groups: 8 mtiles x 4 ntiles; same mtile's 4 ntiles share b%8 -> same XCD
    const int mtile = ((b >> 5) << 3) + (b & 7);
    const int ntile = (b >> 3) & 3;
    const int m0 = mtile * 128, n0 = ntile * 128;
    const int wm = wave >> 1, wn = wave & 1;

    floatx4 acc[4][4];
#pragma unroll
    for (int i = 0; i < 4; ++i)
#pragma unroll
        for (int j = 0; j < 4; ++j) acc[i][j] = (floatx4)0.f;

    float biasj[4];
#pragma unroll
    for (int j = 0; j < 4; ++j) biasj[j] = bias512[n0 + wn * 64 + j * 16 + lr];

    const float* xg = x + (size_t)(m0 + (tid >> 3)) * 256 + (tid & 7) * 4;
    const u16*  wg = Wbig + (size_t)(n0 + (tid >> 2)) * 256 + (tid & 3) * 8;
    char* sAb = (char*)sA;
    char* sBb = (char*)sB;

    for (int kk = 0; kk < 8; ++kk) {
        const int k0 = kk * 32;
        // stage x fp32: 128 rows x 32 k = 16 KB, 4 issues of 256 lanes x 16 B
#pragma unroll
        for (int r = 0; r < 4; ++r)
            __builtin_amdgcn_global_load_lds(AS1(xg + k0 + r * 32 * 256),
                                             AS3(sAb + wave * 1024 + r * 4096), 16, 0, 0);
        // stage Wbig bf16: 128 rows x 32 k = 8 KB, 2 issues
#pragma unroll
        for (int r = 0; r < 2; ++r)
            __builtin_amdgcn_global_load_lds(AS1(wg + k0 + r * 64 * 256),
                                             AS3(sBb + wave * 1024 + r * 4096), 16, 0, 0);
        __syncthreads();

        short8 af[4], bfr[4];
#pragma unroll
        for (int i = 0; i < 4; ++i) {
            const float* p = sA + (wm * 64 + i * 16 + lr) * 32 + quad * 8;
            float4 u0 = *(const float4*)p;
            float4 u1 = *(const float4*)(p + 4);
            af[i][0] = f2bf(u0.x); af[i][1] = f2bf(u0.y);
            af[i][2] = f2bf(u0.z); af[i][3] = f2bf(u0.w);
            af[i][4] = f2bf(u1.x); af[i][5] = f2bf(u1.y);
            af[i][6] = f2bf(u1.z); af[i][7] = f2bf(u1.w);
        }
#pragma unroll
        for (int j = 0; j < 4; ++j) {
            const u16* p = sB + (wn * 64 + j * 16 + lr) * 32 + quad * 8;
            bfr[j] = *(const short8*)p;
        }
#pragma unroll
        for (int i = 0; i < 4; ++i)
#pragma unroll
            for (int j = 0; j < 4; ++j)
                acc[i][j] = __builtin_amdgcn_mfma_f32_16x16x32_bf16(af[i], bfr[j], acc[i][j], 0, 0, 0);
        __syncthreads();
    }

    // epilogue: C/D layout col=lane&15, row=quad*4+reg (m89-verified)
    float* obase = out + ((ntile < 2) ? (size_t)0 : ((size_t)BATCH * 256));
    const int ncol0 = n0 - ((ntile < 2) ? 0 : 256);
#pragma unroll
    for (int i = 0; i < 4; ++i) {
#pragma unroll
        for (int j = 0; j < 4; ++j) {
            const int col = ncol0 + wn * 64 + j * 16 + lr;
#pragma unroll
            for (int r = 0; r < 4; ++r) {
                const size_t row = (size_t)(m0 + wm * 64 + i * 16 + quad * 4 + r);
                obase[row * 256 + col] = acc[i][j][r] + biasj[j];
            }
        }
    }
}

extern "C" void kernel_launch(void* const* d_in, const int* in_sizes, int n_in,
                              void* d_out, int out_size, void* d_ws, size_t ws_size,
                              hipStream_t stream) {
    const float* x    = (const float*)d_in[0];
    const float* Wp   = (const float*)d_in[1];
    const float* bp   = (const float*)d_in[2];
    const float* pre  = (const float*)d_in[3];
    const float* post = (const float*)d_in[4];
    const float* Wc   = (const float*)d_in[5];
    const float* Wo   = (const float*)d_in[6];
    const float* bo   = (const float*)d_in[7];
    float* out = (float*)d_out;

    char* ws = (char*)d_ws;
    float* gate_ws = (float*)(ws);                    // 32 B
    float* bias512 = (float*)(ws + 64);               // 2 KB: [0,256)=c2, [256,512)=c1
    float* A       = (float*)(ws + 4096);             // 256 KB fp32
    u16*  Wbig     = (u16*)(ws + 4096 + 262144);      // 256 KB bf16 [512 x 256]

    float* out_tail = out + TAIL;

    k_align<<<dim3(1), dim3(64), 0, stream>>>(pre, post, gate_ws, out_tail);
    k_makeA<<<dim3(256), dim3(256), 0, stream>>>(Wc, Wp, bp, gate_ws, A, bias512, Wbig);
    k_makeB2<<<dim3(256), dim3(256), 0, stream>>>(Wo, bo, A, bias512, Wbig);
    k_gemm<<<dim3(4096), dim3(256), 0, stream>>>(x, Wbig, bias512, out);
}